// Round 3
// baseline (306.769 us; speedup 1.0000x reference)
//
#include <hip/hip_runtime.h>
#include <stdint.h>

// Scatter-upsample, last-write-wins (largest k):
//   y = zeros((num_nodes,256)); y[col(k), row(k)] = x.flat[k]
//   col(k) = neigh[7*i + max_index[i,f]], k = i*256+f, row(k)=floor(k*256/(T-1)).
//
// R7b: R7 with the compile fix (__builtin_nontemporal_store needs a clang
// ext_vector_type pointer, not HIP's float4 class). Structure unchanged:
//   K0: zero per-node entry counters (655KB).
//   K1: 256 row-WGs (verified ballot + LDS-hash max-k resolver). Winners
//       appended node-major via atomicAdd(count[col]) into table[col*cap+..]
//       (~287K random 4B atomics + 8B stores on a 42MB table -- the only
//       random round, and it avoids the 168MB output buffer).
//   K2: one WAVE per output node: c=count[n] (avg 1.75), compose the 256-f32
//       row in registers (zeros + shfl-broadcast patches), one coalesced
//       nontemporal 16B/lane row store. 168MB written once, sequentially.

#define FEAT 256
#define LOG2FEAT 8
#define BLOCK 256
#define ROW_WGS 256          // one WG per output row r
#define HASH 2048            // per-row hash; max 162*7=1134 distinct cols
#define LOG2HASH 11

typedef float f32x4 __attribute__((ext_vector_type(4)));

extern "C" __global__ __launch_bounds__(BLOCK)
void zero_counts_kernel(int* __restrict__ count, int n)
{
    for (int idx = blockIdx.x * BLOCK + threadIdx.x; idx < n;
         idx += gridDim.x * BLOCK)
        count[idx] = 0;
}

extern "C" __global__ __launch_bounds__(BLOCK)
void row_build_kernel(const int*   __restrict__ mi,     // int32 0..6
                      const int*   __restrict__ neigh,  // int32
                      const float* __restrict__ x,
                      int2*        __restrict__ table,  // [nnodes*cap]
                      int*         __restrict__ count,  // [nnodes]
                      int total,                         // raw_nodes*256
                      int cap)
{
    __shared__ int hkey[HASH];   // col, -1 = empty
    __shared__ int hval[HASH];   // max kp1 for that col

    const int tid = threadIdx.x;
    for (int s = tid; s < HASH; s += BLOCK) { hkey[s] = -1; hval[s] = 0; }
    __syncthreads();

    const int r = blockIdx.x;                             // 0..255
    const unsigned tm1 = (unsigned)(total - 1);
    // k-range [klo, khi] of row r:  row(k) = floor(k*256/(T-1)), last clamped
    const unsigned klo = ((unsigned)r * tm1 + 255u) >> 8;
    const unsigned khi = (r == 255) ? (unsigned)(total - 1)
                       : (((unsigned)(r + 1) * tm1 + 255u) >> 8) - 1u;
    const int i0 = (int)(klo >> 8);                       // node window
    const int i1 = (int)(khi >> 8);                       // (~162 nodes)

    const int lane = tid & 63;
    const int wv   = tid >> 6;                            // wave 0..3

    // software pipeline: prefetch first node's mi row
    int p0 = 0, p1 = 0, p2 = 0, p3 = 0;
    {
        const int ifirst = i0 + wv;
        if (ifirst <= i1) {
            const int* mrow = mi + (ifirst << LOG2FEAT);
            p0 = mrow[lane];       p1 = mrow[64 + lane];
            p2 = mrow[128 + lane]; p3 = mrow[192 + lane];
        }
    }

    for (int i = i0 + wv; i <= i1; i += 4) {
        const int m0 = p0, m1 = p1, m2 = p2, m3 = p3;
        const int inx = i + 4;
        if (inx <= i1) {                                  // prefetch next node
            const int* mrow = mi + (inx << LOG2FEAT);
            p0 = mrow[lane];       p1 = mrow[64 + lane];
            p2 = mrow[128 + lane]; p3 = mrow[192 + lane];
        }
        const int mycol = (lane < 7) ? neigh[i * 7 + lane] : 0;

        const int kbase = i << LOG2FEAT;
        // f-window of node i belonging to row r (interior nodes: [0,255])
        int wlo = (int)klo - kbase; if (wlo < 0)   wlo = 0;
        int whi = (int)khi - kbase; if (whi > 255) whi = 255;

        unsigned long long wm[4];
        #pragma unroll
        for (int j = 0; j < 4; ++j) {
            int lo = wlo - j * 64;  if (lo < 0) lo = 0;
            int hi = whi - j * 64 + 1;
            unsigned long long mhi = (hi >= 64) ? ~0ull
                                   : (hi <= 0)  ? 0ull : ((1ull << hi) - 1ull);
            unsigned long long mlo = (lo >= 64) ? ~0ull : ((1ull << lo) - 1ull);
            wm[j] = mhi & ~mlo;
        }

        unsigned long long b[4][7];
        #pragma unroll
        for (int m = 0; m < 7; ++m) {                     // wave-uniform
            b[0][m] = __ballot(m0 == m);
            b[1][m] = __ballot(m1 == m);
            b[2][m] = __ballot(m2 == m);
            b[3][m] = __ballot(m3 == m);
        }

        if (lane < 7) {                                   // lane = m
            const int m = lane;
            int bestf = -1;
            #pragma unroll
            for (int j = 3; j >= 0; --j) {                // const j: regs only
                if (bestf < 0) {
                    unsigned long long s =
                        (m == 0) ? b[j][0] : (m == 1) ? b[j][1] :
                        (m == 2) ? b[j][2] : (m == 3) ? b[j][3] :
                        (m == 4) ? b[j][4] : (m == 5) ? b[j][5] : b[j][6];
                    unsigned long long t = s & wm[j];
                    if (t) bestf = j * 64 + 63 - __clzll(t);
                }
            }
            if (bestf >= 0) {
                const int kp1 = kbase + bestf + 1;        // globally ordered key
                int slot = mycol & (HASH - 1);
                while (true) {                            // CAS-claim, no locks
                    int prev = atomicCAS(&hkey[slot], -1, mycol);
                    if (prev == -1 || prev == mycol) {
                        atomicMax(&hval[slot], kp1);      // LDS atomic: winner
                        break;
                    }
                    slot = (slot + 1) & (HASH - 1);       // <=1134 keys: no wrap-lock
                }
            }
        }
    }

    __syncthreads();

    // drain: append this row's winners into per-node buckets
    for (int s = tid; s < HASH; s += BLOCK) {
        const int key = hkey[s];
        if (key >= 0) {
            const int kp1  = hval[s];
            const int bits = __float_as_int(x[kp1 - 1]);  // row-local gather
            const int slot = atomicAdd(&count[key], 1);   // distinct cells
            if (slot < cap)                               // P(overflow) ~ 0
                table[(size_t)key * cap + slot] = make_int2(r, bits);
        }
    }
}

extern "C" __global__ __launch_bounds__(BLOCK)
void compose_kernel(float*      __restrict__ out,
                    const int2* __restrict__ table,
                    const int*  __restrict__ count,
                    int nnodes, int cap)
{
    const int lane   = threadIdx.x & 63;
    const int wv     = (blockIdx.x * BLOCK + threadIdx.x) >> 6;
    const int nwaves = gridDim.x * (BLOCK / 64);

    for (int n = wv; n < nnodes; n += nwaves) {
        int c = count[n];                                 // wave-uniform
        if (c > cap) c = cap;
        int2 e = make_int2(-1, 0);
        if (lane < c) e = table[(size_t)n * cap + lane];  // one line per node

        int f0 = 0, f1 = 0, f2 = 0, f3 = 0;
        for (int j = 0; j < c; ++j) {                     // avg 1.75 iters
            const int rj = __shfl(e.x, j);
            const int bj = __shfl(e.y, j);
            if ((rj >> 2) == lane) {
                const int q = rj & 3;
                if      (q == 0) f0 = bj;
                else if (q == 1) f1 = bj;
                else if (q == 2) f2 = bj;
                else             f3 = bj;
            }
        }
        f32x4 f;
        f.x = __int_as_float(f0); f.y = __int_as_float(f1);
        f.z = __int_as_float(f2); f.w = __int_as_float(f3);
        // wave writes one full 1KB row, coalesced, streaming (no reuse)
        f32x4* dst = (f32x4*)(out + ((size_t)n << LOG2FEAT)) + lane;
        __builtin_nontemporal_store(f, dst);
    }
}

extern "C" void kernel_launch(void* const* d_in, const int* in_sizes, int n_in,
                              void* d_out, int out_size, void* d_ws, size_t ws_size,
                              hipStream_t stream) {
    const float* x     = (const float*)d_in[0];   // f32 (40962, 256)
    const int*   mi    = (const int*)d_in[1];     // int32 (40962, 256), 0..6
    const int*   neigh = (const int*)d_in[2];     // int32 (40962*7,)
    float*       out   = (float*)d_out;

    const int total  = in_sizes[0];               // raw_nodes * 256
    const int nnodes = out_size >> LOG2FEAT;      // 163842

    // per-node bucket capacity: appearances ~ Poisson(1.75); pick largest
    // cap the workspace can hold (32 is astronomically safe).
    int cap = 32;
    while (cap > 8 &&
           (size_t)nnodes * (size_t)cap * sizeof(int2) + (size_t)nnodes * 4
               > ws_size)
        cap >>= 1;

    int2* table = (int2*)d_ws;                            // nnodes*cap*8 B
    int*  count = (int*)((char*)d_ws +
                         (size_t)nnodes * (size_t)cap * sizeof(int2));

    zero_counts_kernel<<<dim3(512), dim3(BLOCK), 0, stream>>>(count, nnodes);
    row_build_kernel<<<dim3(ROW_WGS), dim3(BLOCK), 0, stream>>>(
        mi, neigh, x, table, count, total, cap);
    compose_kernel<<<dim3(2048), dim3(BLOCK), 0, stream>>>(
        out, table, count, nnodes, cap);
}

// Round 4
// 281.279 us; speedup vs baseline: 1.0906x; 1.0906x over previous
//
#include <hip/hip_runtime.h>
#include <stdint.h>

// Scatter-upsample, last-write-wins (largest k):
//   y = zeros((num_nodes,256)); y[col(k), row(k)] = x.flat[k]
//   col(k) = neigh[7*i + max_index[i,f]], k = i*256+f, row(k)=floor(k*256/(T-1)).
//
// R8: R7b regressed (285->307) with strictly less output traffic => output
// traffic was NOT the bottleneck. Inferred real bottleneck: the builder has
// always run at 256 WGs = 1 block/CU, 1 wave/SIMD -- a latency-serial chain
// of ~40 node iterations (1-deep prefetch, unprefetched neigh load, 28-ballot
// chain) ~ 110us, previously masked by co-running zeroer WGs.
// Fix:
//   K1 builder: split each row's ~162-node window across SPLIT=8 sub-WGs
//     (2048 WGs = 8 blocks/CU), per-sub-WG 512-slot LDS hash. Cross-chunk
//     duplicates of a (col,row) cell are now possible, so entries carry the
//     packed key (kp1<<8)|row and K2 resolves max-kp1 per cell at patch time.
//   K2 compose: one wave per node, patch in registers, PLAIN coalesced
//     float4 row stores (drop nontemporal -- the other R7b change).

#define FEAT 256
#define LOG2FEAT 8
#define BLOCK 256
#define NROWS 256
#define SPLIT 8              // sub-WGs per row
#define HASH 512             // per-chunk distinct cols <= ~21*7=147
typedef float f32x4 __attribute__((ext_vector_type(4)));

extern "C" __global__ __launch_bounds__(BLOCK)
void zero_counts_kernel(int* __restrict__ count, int n)
{
    for (int idx = blockIdx.x * BLOCK + threadIdx.x; idx < n;
         idx += gridDim.x * BLOCK)
        count[idx] = 0;
}

extern "C" __global__ __launch_bounds__(BLOCK)
void row_build_kernel(const int*   __restrict__ mi,     // int32 0..6
                      const int*   __restrict__ neigh,  // int32
                      const float* __restrict__ x,
                      int2*        __restrict__ table,  // [nnodes*cap]
                      int*         __restrict__ count,  // [nnodes]
                      int total,                         // raw_nodes*256
                      int cap)
{
    __shared__ int hkey[HASH];   // col, -1 = empty
    __shared__ int hval[HASH];   // max kp1 for that col

    const int tid = threadIdx.x;
    for (int s = tid; s < HASH; s += BLOCK) { hkey[s] = -1; hval[s] = 0; }
    __syncthreads();

    const int r   = blockIdx.x / SPLIT;                   // 0..255
    const int sub = blockIdx.x % SPLIT;
    const unsigned tm1 = (unsigned)(total - 1);
    // k-range [klo, khi] of row r:  row(k) = floor(k*256/(T-1)), last clamped
    const unsigned klo = ((unsigned)r * tm1 + 255u) >> 8;
    const unsigned khi = (r == 255) ? (unsigned)(total - 1)
                       : (((unsigned)(r + 1) * tm1 + 255u) >> 8) - 1u;
    const int i0 = (int)(klo >> 8);                       // row node window
    const int i1 = (int)(khi >> 8);                       // (~162 nodes)
    const int len   = i1 - i0 + 1;
    const int chunk = (len + SPLIT - 1) / SPLIT;
    const int ia = i0 + sub * chunk;                      // this WG's chunk
    int ib = ia + chunk - 1; if (ib > i1) ib = i1;

    const int lane = tid & 63;
    const int wv   = tid >> 6;                            // wave 0..3

    // software pipeline: prefetch first node's mi row
    int p0 = 0, p1 = 0, p2 = 0, p3 = 0;
    {
        const int ifirst = ia + wv;
        if (ifirst <= ib) {
            const int* mrow = mi + (ifirst << LOG2FEAT);
            p0 = mrow[lane];       p1 = mrow[64 + lane];
            p2 = mrow[128 + lane]; p3 = mrow[192 + lane];
        }
    }

    for (int i = ia + wv; i <= ib; i += 4) {
        const int m0 = p0, m1 = p1, m2 = p2, m3 = p3;
        const int inx = i + 4;
        if (inx <= ib) {                                  // prefetch next node
            const int* mrow = mi + (inx << LOG2FEAT);
            p0 = mrow[lane];       p1 = mrow[64 + lane];
            p2 = mrow[128 + lane]; p3 = mrow[192 + lane];
        }
        const int mycol = (lane < 7) ? neigh[i * 7 + lane] : 0;

        const int kbase = i << LOG2FEAT;
        // f-window of node i belonging to row r (interior nodes: [0,255])
        int wlo = (int)klo - kbase; if (wlo < 0)   wlo = 0;
        int whi = (int)khi - kbase; if (whi > 255) whi = 255;

        unsigned long long wm[4];
        #pragma unroll
        for (int j = 0; j < 4; ++j) {
            int lo = wlo - j * 64;  if (lo < 0) lo = 0;
            int hi = whi - j * 64 + 1;
            unsigned long long mhi = (hi >= 64) ? ~0ull
                                   : (hi <= 0)  ? 0ull : ((1ull << hi) - 1ull);
            unsigned long long mlo = (lo >= 64) ? ~0ull : ((1ull << lo) - 1ull);
            wm[j] = mhi & ~mlo;
        }

        unsigned long long b[4][7];
        #pragma unroll
        for (int m = 0; m < 7; ++m) {                     // wave-uniform
            b[0][m] = __ballot(m0 == m);
            b[1][m] = __ballot(m1 == m);
            b[2][m] = __ballot(m2 == m);
            b[3][m] = __ballot(m3 == m);
        }

        if (lane < 7) {                                   // lane = m
            const int m = lane;
            int bestf = -1;
            #pragma unroll
            for (int j = 3; j >= 0; --j) {                // const j: regs only
                if (bestf < 0) {
                    unsigned long long s =
                        (m == 0) ? b[j][0] : (m == 1) ? b[j][1] :
                        (m == 2) ? b[j][2] : (m == 3) ? b[j][3] :
                        (m == 4) ? b[j][4] : (m == 5) ? b[j][5] : b[j][6];
                    unsigned long long t = s & wm[j];
                    if (t) bestf = j * 64 + 63 - __clzll(t);
                }
            }
            if (bestf >= 0) {
                const int kp1 = kbase + bestf + 1;        // <= total < 2^24
                int slot = mycol & (HASH - 1);
                while (true) {                            // CAS-claim, no locks
                    int prev = atomicCAS(&hkey[slot], -1, mycol);
                    if (prev == -1 || prev == mycol) {
                        atomicMax(&hval[slot], kp1);      // LDS atomic: winner
                        break;
                    }
                    slot = (slot + 1) & (HASH - 1);       // <=147 keys: no wrap-lock
                }
            }
        }
    }

    __syncthreads();

    // drain: append this chunk's winners into per-node buckets.
    // Cross-chunk dups of one (col,row) possible -> pack kp1 for K2 max-merge.
    for (int s = tid; s < HASH; s += BLOCK) {
        const int key = hkey[s];
        if (key >= 0) {
            const int kp1  = hval[s];
            const int bits = __float_as_int(x[kp1 - 1]);  // chunk-local gather
            const int slot = atomicAdd(&count[key], 1);
            if (slot < cap)                               // P(overflow) ~ 0
                table[(size_t)key * cap + slot] =
                    make_int2((int)(((unsigned)kp1 << 8) | (unsigned)r), bits);
        }
    }
}

extern "C" __global__ __launch_bounds__(BLOCK)
void compose_kernel(float*      __restrict__ out,
                    const int2* __restrict__ table,
                    const int*  __restrict__ count,
                    int nnodes, int cap)
{
    const int lane   = threadIdx.x & 63;
    const int wv     = (blockIdx.x * BLOCK + threadIdx.x) >> 6;
    const int nwaves = gridDim.x * (BLOCK / 64);

    for (int n = wv; n < nnodes; n += nwaves) {
        int c = count[n];                                 // wave-uniform bcast
        if (c > cap) c = cap;
        int2 e = make_int2(0, 0);
        if (lane < c) e = table[(size_t)n * cap + lane];  // 1-2 lines per node

        // lane owns features [4*lane, 4*lane+3]; track max packed key per q
        unsigned k0 = 0, k1 = 0, k2 = 0, k3 = 0;
        int f0 = 0, f1 = 0, f2 = 0, f3 = 0;
        for (int j = 0; j < c; ++j) {                     // avg ~1.8 iters
            const unsigned ex = (unsigned)__shfl(e.x, j); // (kp1<<8)|row
            const int      bj = __shfl(e.y, j);
            const int      rj = (int)(ex & 255u);
            if ((rj >> 2) == lane) {
                const int q = rj & 3;
                if      (q == 0) { if (ex > k0) { k0 = ex; f0 = bj; } }
                else if (q == 1) { if (ex > k1) { k1 = ex; f1 = bj; } }
                else if (q == 2) { if (ex > k2) { k2 = ex; f2 = bj; } }
                else             { if (ex > k3) { k3 = ex; f3 = bj; } }
            }
        }
        f32x4 f;
        f.x = __int_as_float(f0); f.y = __int_as_float(f1);
        f.z = __int_as_float(f2); f.w = __int_as_float(f3);
        // wave writes one full 1KB row, coalesced, full-line (no RFO)
        f32x4* dst = (f32x4*)(out + ((size_t)n << LOG2FEAT)) + lane;
        *dst = f;
    }
}

extern "C" void kernel_launch(void* const* d_in, const int* in_sizes, int n_in,
                              void* d_out, int out_size, void* d_ws, size_t ws_size,
                              hipStream_t stream) {
    const float* x     = (const float*)d_in[0];   // f32 (40962, 256)
    const int*   mi    = (const int*)d_in[1];     // int32 (40962, 256), 0..6
    const int*   neigh = (const int*)d_in[2];     // int32 (40962*7,)
    float*       out   = (float*)d_out;

    const int total  = in_sizes[0];               // raw_nodes * 256
    const int nnodes = out_size >> LOG2FEAT;      // 163842

    // per-node bucket capacity: appearances ~ Poisson(1.77) (+ rare
    // cross-chunk dups); pick largest cap the workspace holds.
    int cap = 32;
    while (cap > 8 &&
           (size_t)nnodes * (size_t)cap * sizeof(int2) + (size_t)nnodes * 4
               > ws_size)
        cap >>= 1;

    int2* table = (int2*)d_ws;                            // nnodes*cap*8 B
    int*  count = (int*)((char*)d_ws +
                         (size_t)nnodes * (size_t)cap * sizeof(int2));

    zero_counts_kernel<<<dim3(256), dim3(BLOCK), 0, stream>>>(count, nnodes);
    row_build_kernel<<<dim3(NROWS * SPLIT), dim3(BLOCK), 0, stream>>>(
        mi, neigh, x, table, count, total, cap);
    compose_kernel<<<dim3(2048), dim3(BLOCK), 0, stream>>>(
        out, table, count, nnodes, cap);
}

// Round 5
// 271.065 us; speedup vs baseline: 1.1317x; 1.0377x over previous
//
#include <hip/hip_runtime.h>
#include <stdint.h>

// Scatter-upsample, last-write-wins (largest k):
//   y = zeros((num_nodes,256)); y[col(k), row(k)] = x.flat[k]
//   col(k) = neigh[7*i + max_index[i,f]], k = i*256+f, row(k)=floor(k*256/(T-1)).
//
// R9: ledger decomposition (R0:283, R1:285, R3:307, R4:281 all fit
// dur ~ 225us harness floor + ours) says ours ~55us vs ~45us floor. This
// round shaves the residue and tests the decomposition:
//  - builder de-hashed: the per-chunk LDS hash deduped ~0.03 keys/chunk
//    (compose's max-merge already resolves (col,row) dups), so winners
//    append DIRECTLY via atomicAdd(count[col]) -- no LDS, no syncthreads,
//    no drain scan; same atomic count as the old drain.
//  - int4 mi loads: 1 dwordx4/node/wave instead of 4 dword loads; ballot
//    bit l maps to f=4l+q, window becomes 4 per-q lane masks.
//  - SPLIT=16 (4096 WGs) for latency hiding.
//  - compose: 1-ahead prefetch of count + first table line (8 entries);
//    rare c>8 (Poisson(1.8) tail, ~13 nodes/run) reloads divergently.
// If dur stays ~281 with floor-level kernels -> harness floor -> ROOFLINE.

#define FEAT 256
#define LOG2FEAT 8
#define BLOCK 256
#define NROWS 256
#define SPLIT 16             // sub-WGs per row (chunk ~ 11 nodes)
typedef float f32x4 __attribute__((ext_vector_type(4)));

extern "C" __global__ __launch_bounds__(BLOCK)
void zero_counts_kernel(int* __restrict__ count, int n)
{
    for (int idx = blockIdx.x * BLOCK + threadIdx.x; idx < n;
         idx += gridDim.x * BLOCK)
        count[idx] = 0;
}

extern "C" __global__ __launch_bounds__(BLOCK)
void row_build_kernel(const int*   __restrict__ mi,     // int32 0..6
                      const int*   __restrict__ neigh,  // int32
                      const float* __restrict__ x,
                      int2*        __restrict__ table,  // [nnodes*cap]
                      int*         __restrict__ count,  // [nnodes]
                      int total,                         // raw_nodes*256
                      int cap)
{
    const int tid = threadIdx.x;
    const int r   = blockIdx.x / SPLIT;                   // 0..255
    const int sub = blockIdx.x % SPLIT;
    const unsigned tm1 = (unsigned)(total - 1);
    // k-range [klo, khi] of row r: row(k)=floor(k*256/(T-1)), last clamped
    const unsigned klo = ((unsigned)r * tm1 + 255u) >> 8;
    const unsigned khi = (r == 255) ? (unsigned)(total - 1)
                       : (((unsigned)(r + 1) * tm1 + 255u) >> 8) - 1u;
    const int i0 = (int)(klo >> 8);                       // row node window
    const int i1 = (int)(khi >> 8);                       // (~162 nodes)
    const int len   = i1 - i0 + 1;
    const int chunk = (len + SPLIT - 1) / SPLIT;
    const int ia = i0 + sub * chunk;                      // this WG's chunk
    int ib = ia + chunk - 1; if (ib > i1) ib = i1;

    const int lane = tid & 63;
    const int wv   = tid >> 6;                            // wave 0..3

    // 1-deep software pipeline: int4 mi row + neigh
    int4 pv = make_int4(7, 7, 7, 7);                      // 7 matches no m
    int  pn = 0;
    {
        const int ifirst = ia + wv;
        if (ifirst <= ib) {
            pv = *(const int4*)(mi + (ifirst << LOG2FEAT) + 4 * lane);
            pn = (lane < 7) ? neigh[ifirst * 7 + lane] : 0;
        }
    }

    for (int i = ia + wv; i <= ib; i += 4) {
        const int4 v    = pv;
        const int mycol = pn;
        const int inx   = i + 4;
        if (inx <= ib) {                                  // prefetch next node
            pv = *(const int4*)(mi + (inx << LOG2FEAT) + 4 * lane);
            pn = (lane < 7) ? neigh[inx * 7 + lane] : 0;
        }

        const int kbase = i << LOG2FEAT;
        // f-window of node i belonging to row r (interior nodes: [0,255])
        int wlo = (int)klo - kbase; if (wlo < 0)   wlo = 0;
        int whi = (int)khi - kbase; if (whi > 255) whi = 255;

        // lane l, component q holds f = 4l+q -> per-q lane masks
        unsigned long long M[4];
        #pragma unroll
        for (int q = 0; q < 4; ++q) {
            int a = wlo - q; if (a < 0) a = 0;
            const int lo_l = (a + 3) >> 2;                // can be 64
            const int b = whi - q;
            unsigned long long mq = 0;
            if (b >= 0 && lo_l <= 63) {
                const int hi_l = b >> 2;                  // <= 63
                mq = (hi_l >= 63) ? ~0ull : ((1ull << (hi_l + 1)) - 1ull);
                if (lo_l > 0) mq &= ~((1ull << lo_l) - 1ull);
            }
            M[q] = mq;
        }

        unsigned long long B[4][7];
        #pragma unroll
        for (int m = 0; m < 7; ++m) {                     // wave-uniform
            B[0][m] = __ballot(v.x == m);
            B[1][m] = __ballot(v.y == m);
            B[2][m] = __ballot(v.z == m);
            B[3][m] = __ballot(v.w == m);
        }

        if (lane < 7) {                                   // lane = m
            const int m = lane;
            int bestf = -1;
            #pragma unroll
            for (int q = 0; q < 4; ++q) {
                const unsigned long long s =
                    (m == 0) ? B[q][0] : (m == 1) ? B[q][1] :
                    (m == 2) ? B[q][2] : (m == 3) ? B[q][3] :
                    (m == 4) ? B[q][4] : (m == 5) ? B[q][5] : B[q][6];
                const unsigned long long t = s & M[q];
                if (t) {
                    const int f = 4 * (63 - __clzll(t)) + q;
                    if (f > bestf) bestf = f;
                }
            }
            if (bestf >= 0) {
                const int kp1  = kbase + bestf + 1;       // <= total < 2^24
                const int bits = __float_as_int(x[kp1 - 1]);
                const int slot = atomicAdd(&count[mycol], 1);
                if (slot < cap)                           // P(overflow) ~ 0
                    table[(size_t)mycol * cap + slot] = make_int2(
                        (int)(((unsigned)kp1 << 8) | (unsigned)r), bits);
            }
        }
    }
}

extern "C" __global__ __launch_bounds__(BLOCK)
void compose_kernel(float*      __restrict__ out,
                    const int2* __restrict__ table,
                    const int*  __restrict__ count,
                    int nnodes, int cap)
{
    const int lane = threadIdx.x & 63;
    const int wv   = (blockIdx.x * BLOCK + threadIdx.x) >> 6;
    const int nw   = gridDim.x * (BLOCK / 64);

    int n = wv;
    int c = 0;
    int2 e = make_int2(0, 0);
    if (n < nnodes) {                                     // prime the pipeline
        c = count[n];
        if (lane < 8) e = table[(size_t)n * cap + lane];  // one 64B line
    }

    while (n < nnodes) {
        const int n2 = n + nw;
        int c2 = 0;
        int2 e2 = make_int2(0, 0);
        if (n2 < nnodes) {                                // prefetch next node
            c2 = count[n2];
            if (lane < 8) e2 = table[(size_t)n2 * cap + lane];
        }

        if (c > cap) c = cap;
        if (c > 8) {                                      // rare (~1e-4) path
            if (lane >= 8 && lane < c)
                e = table[(size_t)n * cap + lane];
        }
        if (lane >= c) { e.x = 0; e.y = 0; }              // invalidate pad

        // lane owns features [4*lane, 4*lane+3]; max packed key per q wins
        unsigned k0 = 0, k1 = 0, k2 = 0, k3 = 0;
        int f0 = 0, f1 = 0, f2 = 0, f3 = 0;
        for (int j = 0; j < c; ++j) {                     // avg ~1.8 iters
            const unsigned ex = (unsigned)__shfl(e.x, j); // (kp1<<8)|row
            const int      bj = __shfl(e.y, j);
            const int      rj = (int)(ex & 255u);
            if ((rj >> 2) == lane) {
                const int q = rj & 3;
                if      (q == 0) { if (ex > k0) { k0 = ex; f0 = bj; } }
                else if (q == 1) { if (ex > k1) { k1 = ex; f1 = bj; } }
                else if (q == 2) { if (ex > k2) { k2 = ex; f2 = bj; } }
                else             { if (ex > k3) { k3 = ex; f3 = bj; } }
            }
        }
        f32x4 f;
        f.x = __int_as_float(f0); f.y = __int_as_float(f1);
        f.z = __int_as_float(f2); f.w = __int_as_float(f3);
        // wave writes one full 1KB row, coalesced, full-line
        f32x4* dst = (f32x4*)(out + ((size_t)n << LOG2FEAT)) + lane;
        *dst = f;

        n = n2; c = c2; e = e2;
    }
}

extern "C" void kernel_launch(void* const* d_in, const int* in_sizes, int n_in,
                              void* d_out, int out_size, void* d_ws, size_t ws_size,
                              hipStream_t stream) {
    const float* x     = (const float*)d_in[0];   // f32 (40962, 256)
    const int*   mi    = (const int*)d_in[1];     // int32 (40962, 256), 0..6
    const int*   neigh = (const int*)d_in[2];     // int32 (40962*7,)
    float*       out   = (float*)d_out;

    const int total  = in_sizes[0];               // raw_nodes * 256
    const int nnodes = out_size >> LOG2FEAT;      // 163842

    // per-node bucket capacity: appearances ~ Poisson(1.8); pick largest
    // cap the workspace holds (32 is astronomically safe).
    int cap = 32;
    while (cap > 8 &&
           (size_t)nnodes * (size_t)cap * sizeof(int2) + (size_t)nnodes * 4
               > ws_size)
        cap >>= 1;

    int2* table = (int2*)d_ws;                            // nnodes*cap*8 B
    int*  count = (int*)((char*)d_ws +
                         (size_t)nnodes * (size_t)cap * sizeof(int2));

    zero_counts_kernel<<<dim3(256), dim3(BLOCK), 0, stream>>>(count, nnodes);
    row_build_kernel<<<dim3(NROWS * SPLIT), dim3(BLOCK), 0, stream>>>(
        mi, neigh, x, table, count, total, cap);
    compose_kernel<<<dim3(2048), dim3(BLOCK), 0, stream>>>(
        out, table, count, nnodes, cap);
}